// Round 15
// baseline (481.344 us; speedup 1.0000x reference)
//
#include <hip/hip_runtime.h>

#define N_NODES 100000
#define N_EDGES 1600000

typedef __attribute__((ext_vector_type(8))) short bf16x8_t;
typedef __attribute__((ext_vector_type(4))) float f32x4_t;
typedef __attribute__((ext_vector_type(4))) _Float16 half4_t;
typedef __attribute__((ext_vector_type(2))) _Float16 half2_t;

static __device__ __forceinline__ unsigned short f2bf(float f) {
    unsigned int u = __float_as_uint(f);
    u += 0x7fffu + ((u >> 16) & 1u);     // RNE
    return (unsigned short)(u >> 16);
}
static __device__ __forceinline__ float bf2f(unsigned short h) {
    return __uint_as_float((unsigned int)h << 16);
}

// ---------------- degree ----------------
__global__ void deg_kernel(const int* __restrict__ dst, int* __restrict__ deg, int E) {
    int i = blockIdx.x * blockDim.x + threadIdx.x;
    if (i < E) atomicAdd(&deg[dst[i]], 1);
}

__global__ void dinv_kernel(const int* __restrict__ deg, float* __restrict__ dinv, int n) {
    int i = blockIdx.x * blockDim.x + threadIdx.x;
    if (i < n) dinv[i] = rsqrtf((float)(deg[i] + 1));   // +1 = self-loop
}

// ---------------- exclusive scan of deg -> rowptr (3 passes) ----------------
__global__ void scan_sums_kernel(const int* __restrict__ deg, int* __restrict__ bsums, int n) {
    __shared__ int sd[256];
    int t = threadIdx.x;
    int base = blockIdx.x * 1024 + t * 4;
    int s = 0;
    #pragma unroll
    for (int j = 0; j < 4; ++j) { int i = base + j; if (i < n) s += deg[i]; }
    sd[t] = s; __syncthreads();
    for (int off = 128; off > 0; off >>= 1) {
        if (t < off) sd[t] += sd[t + off];
        __syncthreads();
    }
    if (t == 0) bsums[blockIdx.x] = sd[0];
}

__global__ void scan_offsets_kernel(int* __restrict__ bsums, int nb, int* __restrict__ rowptr_tail) {
    __shared__ int sd[128];
    int t = threadIdx.x;
    int v = (t < nb) ? bsums[t] : 0;
    sd[t] = v; __syncthreads();
    for (int off = 1; off < 128; off <<= 1) {
        int x = (t >= off) ? sd[t - off] : 0;
        __syncthreads();
        sd[t] += x;
        __syncthreads();
    }
    if (t < nb) bsums[t] = sd[t] - v;      // exclusive
    if (t == 0) *rowptr_tail = N_EDGES;    // rowptr[n]
}

__global__ void scan_final_kernel(const int* __restrict__ deg, const int* __restrict__ bsums,
                                  int* __restrict__ rowptr, int n) {
    __shared__ int sd[256];
    int t = threadIdx.x;
    int base = blockIdx.x * 1024 + t * 4;
    int v[4], pre[4], s = 0;
    #pragma unroll
    for (int j = 0; j < 4; ++j) {
        int i = base + j;
        v[j] = (i < n) ? deg[i] : 0;
        pre[j] = s; s += v[j];
    }
    sd[t] = s;
    int mine = s;
    __syncthreads();
    for (int off = 1; off < 256; off <<= 1) {
        int x = (t >= off) ? sd[t - off] : 0;
        __syncthreads();
        sd[t] += x;
        __syncthreads();
    }
    int excl = sd[t] - mine + bsums[blockIdx.x];
    #pragma unroll
    for (int j = 0; j < 4; ++j) {
        int i = base + j;
        if (i < n) rowptr[i] = excl + pre[j];
    }
}

// ---------------- counting-sort fill: (src, weight) packed as int2 ----------------
__global__ void fill_kernel(const int* __restrict__ src, const int* __restrict__ dst,
                            const float* __restrict__ dinv, const int* __restrict__ rowptr,
                            int* __restrict__ cursor, int2* __restrict__ csr, int E) {
    int i = blockIdx.x * blockDim.x + threadIdx.x;
    if (i >= E) return;
    int s = src[i], d = dst[i];
    int pos = atomicAdd(&cursor[d], 1);
    float w = dinv[s] * dinv[d];
    csr[rowptr[d] + pos] = make_int2(s, __float_as_int(w));
}

// ---------------- x -> fp16 plane ----------------
__global__ void x16_kernel(const float* __restrict__ x, _Float16* __restrict__ y, int total4) {
    int i = blockIdx.x * blockDim.x + threadIdx.x;
    if (i >= total4) return;
    float4 v = *(const float4*)&x[(size_t)i * 4];
    half4_t o;
    o[0] = (_Float16)v.x; o[1] = (_Float16)v.y;
    o[2] = (_Float16)v.z; o[3] = (_Float16)v.w;
    *(half4_t*)&y[(size_t)i * 4] = o;
}

// ---------------- W2fc = W2 @ Wfc -> transposed bf16 hi/lo planes [48][256];
// ---------------- bfc2 = b2 @ Wfc + bfc ----------------
__global__ __launch_bounds__(256) void w2fc_kernel(
        const float* __restrict__ W2, const float* __restrict__ Wfc,
        const float* __restrict__ b2, const float* __restrict__ bfc,
        unsigned short* __restrict__ Th, unsigned short* __restrict__ Tl,
        float* __restrict__ bfc2) {
    __shared__ float wf[64 * 40];
    int t = threadIdx.x;
    for (int i = t; i < 64 * 40; i += 256) wf[i] = Wfc[i];
    __syncthreads();
    float acc[40];
    #pragma unroll
    for (int c = 0; c < 40; ++c) acc[c] = 0.f;
    for (int k = 0; k < 64; ++k) {
        float a = W2[t * 64 + k];
        #pragma unroll
        for (int c = 0; c < 40; ++c) acc[c] += a * wf[k * 40 + c];
    }
    #pragma unroll
    for (int c = 0; c < 40; ++c) {
        unsigned short h = f2bf(acc[c]);
        unsigned short l = f2bf(acc[c] - bf2f(h));
        Th[c * 256 + t] = h;
        Tl[c * 256 + t] = l;
    }
    #pragma unroll
    for (int r = 40; r < 48; ++r) { Th[r * 256 + t] = 0; Tl[r * 256 + t] = 0; }
    if (t < 40) {
        float s = bfc[t];
        for (int k = 0; k < 64; ++k) s += b2[k] * wf[k * 40 + t];
        bfc2[t] = s;
    }
}

// ---------------- W1 [128][256] -> W1t hi/lo bf16 planes [256][128] ----------------
__global__ void w1t_kernel(const float* __restrict__ W1,
                           unsigned short* __restrict__ th, unsigned short* __restrict__ tl) {
    int k = blockIdx.x;          // 0..127
    int n = threadIdx.x;         // 0..255
    float v = W1[k * 256 + n];
    unsigned short h = f2bf(v);
    unsigned short l = f2bf(v - bf2f(h));
    th[n * 128 + k] = h;
    tl[n * 128 + k] = l;
}

// ---------------- gather1: aggx = A_hat @ x16 (fp16 in), hi/lo bf16 planes out ----
__global__ void gather1_kernel(const int* __restrict__ rowptr, const int2* __restrict__ csr,
                               const float* __restrict__ dinv, const _Float16* __restrict__ x,
                               unsigned short* __restrict__ oh, unsigned short* __restrict__ ol,
                               int n) {
    const int lane = threadIdx.x & 63;
    const int wid0 = (blockIdx.x * blockDim.x + threadIdx.x) >> 6;
    const int nwav = (gridDim.x * blockDim.x) >> 6;
    for (int node = wid0; node < n; node += nwav) {
        float di = dinv[node];
        float selfw = di * di;
        int e0 = rowptr[node], e1 = rowptr[node + 1];
        const half2_t sv = *(const half2_t*)&x[(size_t)node * 128 + lane * 2];
        float ax = (float)sv[0] * selfw, ay = (float)sv[1] * selfw;
        int e = e0;
        for (; e + 8 <= e1; e += 8) {
            int2 p[8]; half2_t v[8];
            #pragma unroll
            for (int u = 0; u < 8; ++u) p[u] = csr[e + u];
            #pragma unroll
            for (int u = 0; u < 8; ++u)
                v[u] = *(const half2_t*)&x[(size_t)p[u].x * 128 + lane * 2];
            #pragma unroll
            for (int u = 0; u < 8; ++u) {
                float w = __int_as_float(p[u].y);
                ax += (float)v[u][0] * w; ay += (float)v[u][1] * w;
            }
        }
        for (; e + 4 <= e1; e += 4) {
            int2 p[4]; half2_t v[4];
            #pragma unroll
            for (int u = 0; u < 4; ++u) p[u] = csr[e + u];
            #pragma unroll
            for (int u = 0; u < 4; ++u)
                v[u] = *(const half2_t*)&x[(size_t)p[u].x * 128 + lane * 2];
            #pragma unroll
            for (int u = 0; u < 4; ++u) {
                float w = __int_as_float(p[u].y);
                ax += (float)v[u][0] * w; ay += (float)v[u][1] * w;
            }
        }
        for (; e < e1; ++e) {
            int2 p = csr[e];
            float w = __int_as_float(p.y);
            const half2_t v = *(const half2_t*)&x[(size_t)p.x * 128 + lane * 2];
            ax += (float)v[0] * w; ay += (float)v[1] * w;
        }
        ushort2 hv, lv;
        hv.x = f2bf(ax); lv.x = f2bf(ax - bf2f(hv.x));
        hv.y = f2bf(ay); lv.y = f2bf(ay - bf2f(hv.y));
        *(ushort2*)&oh[(size_t)node * 128 + lane * 2] = hv;
        *(ushort2*)&ol[(size_t)node * 128 + lane * 2] = lv;
    }
}

// ---------------- gather2 (F=40), bias fused, writes d_out ----------------
__global__ void gather2_kernel(const int* __restrict__ rowptr, const int2* __restrict__ csr,
                               const float* __restrict__ dinv, const float* __restrict__ xw,
                               const float* __restrict__ bias, float* __restrict__ out, int n) {
    const int lane = threadIdx.x & 63;
    const int wid0 = (blockIdx.x * blockDim.x + threadIdx.x) >> 6;
    const int nwav = (gridDim.x * blockDim.x) >> 6;
    const int cl = lane < 40 ? lane : 39;
    for (int node = wid0; node < n; node += nwav) {
        float di = dinv[node];
        float selfw = di * di;
        int e0 = rowptr[node], e1 = rowptr[node + 1];
        float acc = xw[(size_t)node * 40 + cl] * selfw;
        int e = e0;
        for (; e + 8 <= e1; e += 8) {
            int2 p[8]; float v[8];
            #pragma unroll
            for (int u = 0; u < 8; ++u) p[u] = csr[e + u];
            #pragma unroll
            for (int u = 0; u < 8; ++u) v[u] = xw[(size_t)p[u].x * 40 + cl];
            #pragma unroll
            for (int u = 0; u < 8; ++u) acc += v[u] * __int_as_float(p[u].y);
        }
        for (; e < e1; ++e) {
            int2 p = csr[e];
            acc += xw[(size_t)p.x * 40 + cl] * __int_as_float(p.y);
        }
        acc += bias[cl];
        if (lane < 40) out[(size_t)node * 40 + lane] = acc;
    }
}

// ---------------- gemm1: LDS-free split-bf16 MFMA ----------------
// h1 = relu(aggx[M,128] @ W1[128,256] + b1); A/B hi-lo bf16 planes, W1t = [N][K].
// All fragments loaded straight from global (A streamed, B L2-resident).
// 4 waves (2x2): wave tile 64x64; no LDS, no barriers.
__global__ __launch_bounds__(256) void gemm1_mfma(
        const unsigned short* __restrict__ Ah, const unsigned short* __restrict__ Al,
        const unsigned short* __restrict__ Bh, const unsigned short* __restrict__ Bl,
        const float* __restrict__ bias,
        unsigned short* __restrict__ Ch, unsigned short* __restrict__ Cl, int M) {
    constexpr int K = 128, N = 256;
    const int t = threadIdx.x;
    const int wave = t >> 6, lane = t & 63;
    const int wm = wave >> 1, wn = wave & 1;
    const int l15 = lane & 15, k8 = (lane >> 4) * 8;
    const int m_base = blockIdx.x * 128 + wm * 64;
    const int n_base = blockIdx.y * 128 + wn * 64;

    f32x4_t acc[4][4] = {};

    #pragma unroll
    for (int k0 = 0; k0 < K; k0 += 32) {
        bf16x8_t fah[4], fal[4];
        #pragma unroll
        for (int i = 0; i < 4; ++i) {
            int row = m_base + i * 16 + l15; if (row > M - 1) row = M - 1;
            fah[i] = *(const bf16x8_t*)&Ah[(size_t)row * K + k0 + k8];
            fal[i] = *(const bf16x8_t*)&Al[(size_t)row * K + k0 + k8];
        }
        #pragma unroll
        for (int j = 0; j < 4; ++j) {
            int col = n_base + j * 16 + l15;
            bf16x8_t fbh = *(const bf16x8_t*)&Bh[(size_t)col * K + k0 + k8];
            bf16x8_t fbl = *(const bf16x8_t*)&Bl[(size_t)col * K + k0 + k8];
            #pragma unroll
            for (int i = 0; i < 4; ++i) {
                acc[i][j] = __builtin_amdgcn_mfma_f32_16x16x32_bf16(fah[i], fbh, acc[i][j], 0, 0, 0);
                acc[i][j] = __builtin_amdgcn_mfma_f32_16x16x32_bf16(fah[i], fbl, acc[i][j], 0, 0, 0);
                acc[i][j] = __builtin_amdgcn_mfma_f32_16x16x32_bf16(fal[i], fbh, acc[i][j], 0, 0, 0);
            }
        }
    }

    const int r4 = (lane >> 4) * 4;
    #pragma unroll
    for (int j = 0; j < 4; ++j) {
        int col = n_base + j * 16 + l15;
        float bv = bias[col];
        #pragma unroll
        for (int i = 0; i < 4; ++i) {
            #pragma unroll
            for (int r = 0; r < 4; ++r) {
                int row = m_base + i * 16 + r4 + r;
                if (row < M) {
                    float v = fmaxf(acc[i][j][r] + bv, 0.f);
                    unsigned short h = f2bf(v);
                    unsigned short l = f2bf(v - bf2f(h));
                    Ch[(size_t)row * N + col] = h;
                    Cl[(size_t)row * N + col] = l;
                }
            }
        }
    }
}

// ---------------- gemm2: LDS-free split-bf16 MFMA ----------------
// h1w[M,40] = h1[M,256] @ W2fc[256,40]; W2fcT hi/lo [48][256] (rows 40..47 zero).
// 4 waves: wave owns 32 rows (2 m-tiles) x 48 cols (3 n-tiles). No LDS/barriers.
__global__ __launch_bounds__(256) void gemm2_mfma(
        const unsigned short* __restrict__ Ah, const unsigned short* __restrict__ Al,
        const unsigned short* __restrict__ Bh, const unsigned short* __restrict__ Bl,
        float* __restrict__ C, int M) {
    constexpr int K = 256;
    const int t = threadIdx.x;
    const int wave = t >> 6, lane = t & 63;
    const int l15 = lane & 15, k8 = (lane >> 4) * 8;
    const int m_base = blockIdx.x * 128 + wave * 32;

    f32x4_t acc[2][3] = {};

    #pragma unroll
    for (int k0 = 0; k0 < K; k0 += 32) {
        bf16x8_t fah[2], fal[2];
        #pragma unroll
        for (int i = 0; i < 2; ++i) {
            int row = m_base + i * 16 + l15; if (row > M - 1) row = M - 1;
            fah[i] = *(const bf16x8_t*)&Ah[(size_t)row * K + k0 + k8];
            fal[i] = *(const bf16x8_t*)&Al[(size_t)row * K + k0 + k8];
        }
        #pragma unroll
        for (int j = 0; j < 3; ++j) {
            int col = j * 16 + l15;
            bf16x8_t fbh = *(const bf16x8_t*)&Bh[(size_t)col * K + k0 + k8];
            bf16x8_t fbl = *(const bf16x8_t*)&Bl[(size_t)col * K + k0 + k8];
            #pragma unroll
            for (int i = 0; i < 2; ++i) {
                acc[i][j] = __builtin_amdgcn_mfma_f32_16x16x32_bf16(fah[i], fbh, acc[i][j], 0, 0, 0);
                acc[i][j] = __builtin_amdgcn_mfma_f32_16x16x32_bf16(fah[i], fbl, acc[i][j], 0, 0, 0);
                acc[i][j] = __builtin_amdgcn_mfma_f32_16x16x32_bf16(fal[i], fbh, acc[i][j], 0, 0, 0);
            }
        }
    }

    const int r4 = (lane >> 4) * 4;
    #pragma unroll
    for (int i = 0; i < 2; ++i)
        #pragma unroll
        for (int j = 0; j < 3; ++j) {
            int col = j * 16 + l15;
            if (col < 40) {
                #pragma unroll
                for (int r = 0; r < 4; ++r) {
                    int row = m_base + i * 16 + r4 + r;
                    if (row < M) C[(size_t)row * 40 + col] = acc[i][j][r];
                }
            }
        }
}

extern "C" void kernel_launch(void* const* d_in, const int* in_sizes, int n_in,
                              void* d_out, int out_size, void* d_ws, size_t ws_size,
                              hipStream_t stream) {
    const float* x   = (const float*)d_in[0];
    const int*   ei  = (const int*)d_in[1];
    const float* W1  = (const float*)d_in[2];
    const float* b1  = (const float*)d_in[3];
    const float* W2  = (const float*)d_in[4];
    const float* b2  = (const float*)d_in[5];
    const float* Wfc = (const float*)d_in[6];
    const float* bfc = (const float*)d_in[7];
    float* out = (float*)d_out;

    const int n = N_NODES, E = N_EDGES;
    const int* src = ei;
    const int* dst = ei + E;

    char* ws = (char*)d_ws;
    int*            deg    = (int*)(ws + 0);            // 400 KB (reused as cursor)
    float*          dinv   = (float*)(ws + 409600);     // 400 KB
    int*            rowptr = (int*)(ws + 819200);       // ~400 KB
    int*            bsums  = (int*)(ws + 1219584);      // 512 B
    float*          bfc2   = (float*)(ws + 1220096);    // 160 B
    unsigned short* w2th   = (unsigned short*)(ws + 1220608);   // 24 KB [48][256]
    unsigned short* w2tl   = (unsigned short*)(ws + 1245184);   // 24 KB
    unsigned short* w1th   = (unsigned short*)(ws + 1269760);   // 64 KB
    unsigned short* w1tl   = (unsigned short*)(ws + 1335296);   // 64 KB
    int2*           csr    = (int2*)(ws + 1400832);     // 12.8 MB
    _Float16*       x16    = (_Float16*)(ws + 14200832);        // 25.6 MB
    unsigned short* aggxh  = (unsigned short*)(ws + 39800832);  // 25.6 MB
    unsigned short* aggxl  = (unsigned short*)(ws + 65400832);  // 25.6 MB
    unsigned short* h1h    = (unsigned short*)(ws + 91000832);  // 51.2 MB
    unsigned short* h1l    = (unsigned short*)(ws + 142200832); // 51.2 MB
    float*          h1w    = (float*)(ws + 193400832);  // 16 MB ([100k][40])

    const int nb = (n + 1023) / 1024;  // 98 scan blocks

    // ---- CSR build (by dst) + weight precomputes + x fp16 plane ----
    hipMemsetAsync(deg, 0, (size_t)n * sizeof(int), stream);
    deg_kernel<<<(E + 255) / 256, 256, 0, stream>>>(dst, deg, E);
    dinv_kernel<<<(n + 255) / 256, 256, 0, stream>>>(deg, dinv, n);
    scan_sums_kernel<<<nb, 256, 0, stream>>>(deg, bsums, n);
    scan_offsets_kernel<<<1, 128, 0, stream>>>(bsums, nb, rowptr + n);
    scan_final_kernel<<<nb, 256, 0, stream>>>(deg, bsums, rowptr, n);
    hipMemsetAsync(deg, 0, (size_t)n * sizeof(int), stream);  // deg -> cursor
    fill_kernel<<<(E + 255) / 256, 256, 0, stream>>>(src, dst, dinv, rowptr, deg, csr, E);
    w2fc_kernel<<<1, 256, 0, stream>>>(W2, Wfc, b2, bfc, w2th, w2tl, bfc2);
    w1t_kernel<<<128, 256, 0, stream>>>(W1, w1th, w1tl);
    x16_kernel<<<(n * 128 / 4 + 255) / 256, 256, 0, stream>>>(x, x16, n * 32);

    // ---- layer 1: aggx(hi/lo bf16) = A_hat @ x16; h1(hi/lo) = relu(aggx@W1+b1) ----
    gather1_kernel<<<2048, 256, 0, stream>>>(rowptr, csr, dinv, x16, aggxh, aggxl, n);
    gemm1_mfma<<<dim3((n + 127) / 128, 2), 256, 0, stream>>>(
        aggxh, aggxl, w1th, w1tl, b1, h1h, h1l, n);

    // ---- layer 2 + FC folded: out = A_hat @ (h1 @ W2fc) + bfc2 ----
    gemm2_mfma<<<(n + 127) / 128, 256, 0, stream>>>(h1h, h1l, w2th, w2tl, h1w, n);
    gather2_kernel<<<2048, 256, 0, stream>>>(rowptr, csr, dinv, h1w, bfc2, out, n);
}

// Round 16
// 379.583 us; speedup vs baseline: 1.2681x; 1.2681x over previous
//
#include <hip/hip_runtime.h>

#define N_NODES 100000
#define N_EDGES 1600000

typedef __attribute__((ext_vector_type(8))) _Float16 half8_t;
typedef __attribute__((ext_vector_type(4))) float f32x4_t;
typedef __attribute__((ext_vector_type(4))) _Float16 half4_t;
typedef __attribute__((ext_vector_type(2))) _Float16 half2_t;

// ---------------- degree ----------------
__global__ void deg_kernel(const int* __restrict__ dst, int* __restrict__ deg, int E) {
    int i = blockIdx.x * blockDim.x + threadIdx.x;
    if (i < E) atomicAdd(&deg[dst[i]], 1);
}

__global__ void dinv_kernel(const int* __restrict__ deg, float* __restrict__ dinv, int n) {
    int i = blockIdx.x * blockDim.x + threadIdx.x;
    if (i < n) dinv[i] = rsqrtf((float)(deg[i] + 1));   // +1 = self-loop
}

// ---------------- exclusive scan of deg -> rowptr (3 passes) ----------------
__global__ void scan_sums_kernel(const int* __restrict__ deg, int* __restrict__ bsums, int n) {
    __shared__ int sd[256];
    int t = threadIdx.x;
    int base = blockIdx.x * 1024 + t * 4;
    int s = 0;
    #pragma unroll
    for (int j = 0; j < 4; ++j) { int i = base + j; if (i < n) s += deg[i]; }
    sd[t] = s; __syncthreads();
    for (int off = 128; off > 0; off >>= 1) {
        if (t < off) sd[t] += sd[t + off];
        __syncthreads();
    }
    if (t == 0) bsums[blockIdx.x] = sd[0];
}

__global__ void scan_offsets_kernel(int* __restrict__ bsums, int nb, int* __restrict__ rowptr_tail) {
    __shared__ int sd[128];
    int t = threadIdx.x;
    int v = (t < nb) ? bsums[t] : 0;
    sd[t] = v; __syncthreads();
    for (int off = 1; off < 128; off <<= 1) {
        int x = (t >= off) ? sd[t - off] : 0;
        __syncthreads();
        sd[t] += x;
        __syncthreads();
    }
    if (t < nb) bsums[t] = sd[t] - v;      // exclusive
    if (t == 0) *rowptr_tail = N_EDGES;    // rowptr[n]
}

__global__ void scan_final_kernel(const int* __restrict__ deg, const int* __restrict__ bsums,
                                  int* __restrict__ rowptr, int n) {
    __shared__ int sd[256];
    int t = threadIdx.x;
    int base = blockIdx.x * 1024 + t * 4;
    int v[4], pre[4], s = 0;
    #pragma unroll
    for (int j = 0; j < 4; ++j) {
        int i = base + j;
        v[j] = (i < n) ? deg[i] : 0;
        pre[j] = s; s += v[j];
    }
    sd[t] = s;
    int mine = s;
    __syncthreads();
    for (int off = 1; off < 256; off <<= 1) {
        int x = (t >= off) ? sd[t - off] : 0;
        __syncthreads();
        sd[t] += x;
        __syncthreads();
    }
    int excl = sd[t] - mine + bsums[blockIdx.x];
    #pragma unroll
    for (int j = 0; j < 4; ++j) {
        int i = base + j;
        if (i < n) rowptr[i] = excl + pre[j];
    }
}

// ---------------- counting-sort fill: (src, weight) packed as int2 ----------------
__global__ void fill_kernel(const int* __restrict__ src, const int* __restrict__ dst,
                            const float* __restrict__ dinv, const int* __restrict__ rowptr,
                            int* __restrict__ cursor, int2* __restrict__ csr, int E) {
    int i = blockIdx.x * blockDim.x + threadIdx.x;
    if (i >= E) return;
    int s = src[i], d = dst[i];
    int pos = atomicAdd(&cursor[d], 1);
    float w = dinv[s] * dinv[d];
    csr[rowptr[d] + pos] = make_int2(s, __float_as_int(w));
}

// ---------------- x -> fp16 plane ----------------
__global__ void x16_kernel(const float* __restrict__ x, _Float16* __restrict__ y, int total4) {
    int i = blockIdx.x * blockDim.x + threadIdx.x;
    if (i >= total4) return;
    float4 v = *(const float4*)&x[(size_t)i * 4];
    half4_t o;
    o[0] = (_Float16)v.x; o[1] = (_Float16)v.y;
    o[2] = (_Float16)v.z; o[3] = (_Float16)v.w;
    *(half4_t*)&y[(size_t)i * 4] = o;
}

// ---------------- W2fc = W2 @ Wfc -> transposed fp16 [48][256]; bfc2 = b2@Wfc+bfc --
__global__ __launch_bounds__(256) void w2fc_kernel(
        const float* __restrict__ W2, const float* __restrict__ Wfc,
        const float* __restrict__ b2, const float* __restrict__ bfc,
        _Float16* __restrict__ T16, float* __restrict__ bfc2) {
    __shared__ float wf[64 * 40];
    int t = threadIdx.x;
    for (int i = t; i < 64 * 40; i += 256) wf[i] = Wfc[i];
    __syncthreads();
    float acc[40];
    #pragma unroll
    for (int c = 0; c < 40; ++c) acc[c] = 0.f;
    for (int k = 0; k < 64; ++k) {
        float a = W2[t * 64 + k];
        #pragma unroll
        for (int c = 0; c < 40; ++c) acc[c] += a * wf[k * 40 + c];
    }
    #pragma unroll
    for (int c = 0; c < 40; ++c) T16[c * 256 + t] = (_Float16)acc[c];
    #pragma unroll
    for (int r = 40; r < 48; ++r) T16[r * 256 + t] = (_Float16)0.f;
    if (t < 40) {
        float s = bfc[t];
        for (int k = 0; k < 64; ++k) s += b2[k] * wf[k * 40 + t];
        bfc2[t] = s;
    }
}

// ---------------- W1 [128][256] -> W1t fp16 [256][128] ----------------
__global__ void w1t_kernel(const float* __restrict__ W1, _Float16* __restrict__ t16) {
    int k = blockIdx.x;          // 0..127
    int n = threadIdx.x;         // 0..255
    t16[n * 128 + k] = (_Float16)W1[k * 256 + n];
}

// ---------------- gather1: aggx(fp16) = A_hat @ x16 ----------------
__global__ void gather1_kernel(const int* __restrict__ rowptr, const int2* __restrict__ csr,
                               const float* __restrict__ dinv, const _Float16* __restrict__ x,
                               _Float16* __restrict__ o16, int n) {
    const int lane = threadIdx.x & 63;
    const int wid0 = (blockIdx.x * blockDim.x + threadIdx.x) >> 6;
    const int nwav = (gridDim.x * blockDim.x) >> 6;
    for (int node = wid0; node < n; node += nwav) {
        float di = dinv[node];
        float selfw = di * di;
        int e0 = rowptr[node], e1 = rowptr[node + 1];
        const half2_t sv = *(const half2_t*)&x[(size_t)node * 128 + lane * 2];
        float ax = (float)sv[0] * selfw, ay = (float)sv[1] * selfw;
        int e = e0;
        for (; e + 8 <= e1; e += 8) {
            int2 p[8]; half2_t v[8];
            #pragma unroll
            for (int u = 0; u < 8; ++u) p[u] = csr[e + u];
            #pragma unroll
            for (int u = 0; u < 8; ++u)
                v[u] = *(const half2_t*)&x[(size_t)p[u].x * 128 + lane * 2];
            #pragma unroll
            for (int u = 0; u < 8; ++u) {
                float w = __int_as_float(p[u].y);
                ax += (float)v[u][0] * w; ay += (float)v[u][1] * w;
            }
        }
        for (; e + 4 <= e1; e += 4) {
            int2 p[4]; half2_t v[4];
            #pragma unroll
            for (int u = 0; u < 4; ++u) p[u] = csr[e + u];
            #pragma unroll
            for (int u = 0; u < 4; ++u)
                v[u] = *(const half2_t*)&x[(size_t)p[u].x * 128 + lane * 2];
            #pragma unroll
            for (int u = 0; u < 4; ++u) {
                float w = __int_as_float(p[u].y);
                ax += (float)v[u][0] * w; ay += (float)v[u][1] * w;
            }
        }
        for (; e < e1; ++e) {
            int2 p = csr[e];
            float w = __int_as_float(p.y);
            const half2_t v = *(const half2_t*)&x[(size_t)p.x * 128 + lane * 2];
            ax += (float)v[0] * w; ay += (float)v[1] * w;
        }
        half2_t ov; ov[0] = (_Float16)ax; ov[1] = (_Float16)ay;
        *(half2_t*)&o16[(size_t)node * 128 + lane * 2] = ov;
    }
}

// ---------------- gather2 (F=40), bias fused, writes d_out ----------------
__global__ void gather2_kernel(const int* __restrict__ rowptr, const int2* __restrict__ csr,
                               const float* __restrict__ dinv, const float* __restrict__ xw,
                               const float* __restrict__ bias, float* __restrict__ out, int n) {
    const int lane = threadIdx.x & 63;
    const int wid0 = (blockIdx.x * blockDim.x + threadIdx.x) >> 6;
    const int nwav = (gridDim.x * blockDim.x) >> 6;
    const int cl = lane < 40 ? lane : 39;
    for (int node = wid0; node < n; node += nwav) {
        float di = dinv[node];
        float selfw = di * di;
        int e0 = rowptr[node], e1 = rowptr[node + 1];
        float acc = xw[(size_t)node * 40 + cl] * selfw;
        int e = e0;
        for (; e + 8 <= e1; e += 8) {
            int2 p[8]; float v[8];
            #pragma unroll
            for (int u = 0; u < 8; ++u) p[u] = csr[e + u];
            #pragma unroll
            for (int u = 0; u < 8; ++u) v[u] = xw[(size_t)p[u].x * 40 + cl];
            #pragma unroll
            for (int u = 0; u < 8; ++u) acc += v[u] * __int_as_float(p[u].y);
        }
        for (; e < e1; ++e) {
            int2 p = csr[e];
            acc += xw[(size_t)p.x * 40 + cl] * __int_as_float(p.y);
        }
        acc += bias[cl];
        if (lane < 40) out[(size_t)node * 40 + lane] = acc;
    }
}

// ---------------- gemm1: fp16 MFMA, LDS-staged ----------------
// h1(fp16) = relu(aggx[M,128] @ W1[128,256] + b1); W1t fp16 [N][K].
// 4 waves (2x2), BM=BN=128, BK=32, LDS [r][LDK=40]; 1 MFMA per frag pair.
__global__ __launch_bounds__(256) void gemm1_mfma(
        const _Float16* __restrict__ A16, const _Float16* __restrict__ B16,
        const float* __restrict__ bias, _Float16* __restrict__ C16, int M) {
    constexpr int K = 128, N = 256, LDK = 40;
    __shared__ _Float16 sA[128 * LDK];
    __shared__ _Float16 sB[128 * LDK];
    const int t = threadIdx.x;
    const int m0 = blockIdx.x * 128, n0 = blockIdx.y * 128;
    const int wave = t >> 6, lane = t & 63;
    const int wm = wave >> 1, wn = wave & 1;
    const int l15 = lane & 15, k8 = (lane >> 4) * 8;

    f32x4_t acc[4][4] = {};

    for (int k0 = 0; k0 < K; k0 += 32) {
        #pragma unroll
        for (int u = 0; u < 2; ++u) {
            int idx = t + u * 256;
            int r = idx >> 2, c = (idx & 3) * 8;
            int gr = m0 + r; if (gr > M - 1) gr = M - 1;
            *(uint4*)&sA[r * LDK + c] = *(const uint4*)&A16[(size_t)gr * K + k0 + c];
            int bn = n0 + r;
            *(uint4*)&sB[r * LDK + c] = *(const uint4*)&B16[(size_t)bn * K + k0 + c];
        }
        __syncthreads();
        half8_t fa[4], fb[4];
        #pragma unroll
        for (int i = 0; i < 4; ++i) {
            int m = wm * 64 + i * 16 + l15;
            fa[i] = *(const half8_t*)&sA[m * LDK + k8];
            int nn = wn * 64 + i * 16 + l15;
            fb[i] = *(const half8_t*)&sB[nn * LDK + k8];
        }
        #pragma unroll
        for (int i = 0; i < 4; ++i)
            #pragma unroll
            for (int j = 0; j < 4; ++j)
                acc[i][j] = __builtin_amdgcn_mfma_f32_16x16x32_f16(fa[i], fb[j], acc[i][j], 0, 0, 0);
        __syncthreads();
    }

    const int r4 = (lane >> 4) * 4;
    #pragma unroll
    for (int j = 0; j < 4; ++j) {
        int col = n0 + wn * 64 + j * 16 + l15;
        float bv = bias[col];
        #pragma unroll
        for (int i = 0; i < 4; ++i) {
            #pragma unroll
            for (int r = 0; r < 4; ++r) {
                int row = m0 + wm * 64 + i * 16 + r4 + r;
                if (row < M) {
                    float v = fmaxf(acc[i][j][r] + bv, 0.f);
                    C16[(size_t)row * N + col] = (_Float16)v;
                }
            }
        }
    }
}

// ---------------- gemm2: fp16 MFMA, LDS-staged ----------------
// h1w[M,40] = h1[M,256] @ W2fc[256,40]; W2fcT fp16 [48][256] (rows 40..47 zero).
// 4 waves, BM=128 (wave owns 32 rows), 3 n-tiles.
__global__ __launch_bounds__(256) void gemm2_mfma(
        const _Float16* __restrict__ A16, const _Float16* __restrict__ B16,
        float* __restrict__ C, int M) {
    constexpr int K = 256, LDK = 40;
    __shared__ _Float16 sA[128 * LDK];
    __shared__ _Float16 sB[48 * LDK];
    const int t = threadIdx.x;
    const int m0 = blockIdx.x * 128;
    const int wave = t >> 6, lane = t & 63;
    const int l15 = lane & 15, k8 = (lane >> 4) * 8;

    f32x4_t acc[2][3] = {};

    for (int k0 = 0; k0 < K; k0 += 32) {
        #pragma unroll
        for (int u = 0; u < 2; ++u) {
            int idx = t + u * 256;
            int r = idx >> 2, c = (idx & 3) * 8;
            int gr = m0 + r; if (gr > M - 1) gr = M - 1;
            *(uint4*)&sA[r * LDK + c] = *(const uint4*)&A16[(size_t)gr * K + k0 + c];
        }
        if (t < 192) {
            int r = t >> 2, c = (t & 3) * 8;
            *(uint4*)&sB[r * LDK + c] = *(const uint4*)&B16[(size_t)r * K + k0 + c];
        }
        __syncthreads();
        half8_t fa[2], fb[3];
        #pragma unroll
        for (int i = 0; i < 2; ++i) {
            int m = wave * 32 + i * 16 + l15;
            fa[i] = *(const half8_t*)&sA[m * LDK + k8];
        }
        #pragma unroll
        for (int j = 0; j < 3; ++j) {
            int nn = j * 16 + l15;
            fb[j] = *(const half8_t*)&sB[nn * LDK + k8];
        }
        #pragma unroll
        for (int i = 0; i < 2; ++i)
            #pragma unroll
            for (int j = 0; j < 3; ++j)
                acc[i][j] = __builtin_amdgcn_mfma_f32_16x16x32_f16(fa[i], fb[j], acc[i][j], 0, 0, 0);
        __syncthreads();
    }

    const int r4 = (lane >> 4) * 4;
    #pragma unroll
    for (int i = 0; i < 2; ++i)
        #pragma unroll
        for (int j = 0; j < 3; ++j) {
            int col = j * 16 + l15;
            if (col < 40) {
                #pragma unroll
                for (int r = 0; r < 4; ++r) {
                    int row = m0 + wave * 32 + i * 16 + r4 + r;
                    if (row < M) C[(size_t)row * 40 + col] = acc[i][j][r];
                }
            }
        }
}

extern "C" void kernel_launch(void* const* d_in, const int* in_sizes, int n_in,
                              void* d_out, int out_size, void* d_ws, size_t ws_size,
                              hipStream_t stream) {
    const float* x   = (const float*)d_in[0];
    const int*   ei  = (const int*)d_in[1];
    const float* W1  = (const float*)d_in[2];
    const float* b1  = (const float*)d_in[3];
    const float* W2  = (const float*)d_in[4];
    const float* b2  = (const float*)d_in[5];
    const float* Wfc = (const float*)d_in[6];
    const float* bfc = (const float*)d_in[7];
    float* out = (float*)d_out;

    const int n = N_NODES, E = N_EDGES;
    const int* src = ei;
    const int* dst = ei + E;

    char* ws = (char*)d_ws;
    int*       deg    = (int*)(ws + 0);            // 400 KB (reused as cursor)
    float*     dinv   = (float*)(ws + 409600);     // 400 KB
    int*       rowptr = (int*)(ws + 819200);       // ~400 KB
    int*       bsums  = (int*)(ws + 1219584);      // 512 B
    float*     bfc2   = (float*)(ws + 1220096);    // 512 B
    _Float16*  w2t16  = (_Float16*)(ws + 1220608); // 24 KB [48][256]
    _Float16*  w1t16  = (_Float16*)(ws + 1245184); // 64 KB [256][128]
    int2*      csr    = (int2*)(ws + 1310720);     // 12.8 MB
    _Float16*  x16    = (_Float16*)(ws + 14110720);  // 25.6 MB
    _Float16*  aggx16 = (_Float16*)(ws + 39710720);  // 25.6 MB
    _Float16*  h116   = (_Float16*)(ws + 65310720);  // 51.2 MB
    float*     h1w    = (float*)(ws + 116510720);    // 16 MB ([100k][40])

    const int nb = (n + 1023) / 1024;  // 98 scan blocks

    // ---- CSR build (by dst) + weight precomputes + x fp16 plane ----
    hipMemsetAsync(deg, 0, (size_t)n * sizeof(int), stream);
    deg_kernel<<<(E + 255) / 256, 256, 0, stream>>>(dst, deg, E);
    dinv_kernel<<<(n + 255) / 256, 256, 0, stream>>>(deg, dinv, n);
    scan_sums_kernel<<<nb, 256, 0, stream>>>(deg, bsums, n);
    scan_offsets_kernel<<<1, 128, 0, stream>>>(bsums, nb, rowptr + n);
    scan_final_kernel<<<nb, 256, 0, stream>>>(deg, bsums, rowptr, n);
    hipMemsetAsync(deg, 0, (size_t)n * sizeof(int), stream);  // deg -> cursor
    fill_kernel<<<(E + 255) / 256, 256, 0, stream>>>(src, dst, dinv, rowptr, deg, csr, E);
    w2fc_kernel<<<1, 256, 0, stream>>>(W2, Wfc, b2, bfc, w2t16, bfc2);
    w1t_kernel<<<128, 256, 0, stream>>>(W1, w1t16);
    x16_kernel<<<(n * 128 / 4 + 255) / 256, 256, 0, stream>>>(x, x16, n * 32);

    // ---- layer 1: aggx(fp16) = A_hat @ x16; h1(fp16) = relu(aggx @ W1 + b1) ----
    gather1_kernel<<<2048, 256, 0, stream>>>(rowptr, csr, dinv, x16, aggx16, n);
    gemm1_mfma<<<dim3((n + 127) / 128, 2), 256, 0, stream>>>(
        aggx16, w1t16, b1, h116, n);

    // ---- layer 2 + FC folded: out = A_hat @ (h1 @ W2fc) + bfc2 ----
    gemm2_mfma<<<(n + 127) / 128, 256, 0, stream>>>(h116, w2t16, h1w, n);
    gather2_kernel<<<2048, 256, 0, stream>>>(rowptr, csr, dinv, h1w, bfc2, out, n);
}